// Round 11
// baseline (3146.381 us; speedup 1.0000x reference)
//
#include <hip/hip_runtime.h>

// LSTM encoder: V=32000 E=512 U=1024 L=2, B=64 T=256.
// Round 11: batch-group scan. The LSTM recurrence is independent across
// batch rows -> split B=64 into 4 groups of 16 rows; each group runs its
// own 64-block-per-layer barrier (vs one 512-block barrier): 8x smaller
// straggler pool, 63-wide gather. 16-row blocks give 1 A-frag reused by 4
// resident B-frags (64 cols/block) -> L2 h-traffic halves again. L1 keeps
// U1 resident (asm-pinned: r10's VGPR=108 showed the compiler demoted
// weights to per-step reloads) and streams W1 in the hidden overlap window.
// zred stride 66 (write conflict 4-way -> 2-way=free); out store deferred.

typedef _Float16 f16;
typedef _Float16 f16x8 __attribute__((ext_vector_type(8)));
typedef _Float16 f16x4 __attribute__((ext_vector_type(4)));
typedef float f32x4 __attribute__((ext_vector_type(4)));

__device__ __forceinline__ f32x4 mfma16x32(f16x8 a, f16x8 b, f32x4 c) {
  return __builtin_amdgcn_mfma_f32_16x16x32_f16(a, b, c, 0, 0, 0);
}

__device__ __forceinline__ void gl_lds16(const void* g, void* l) {
  __builtin_amdgcn_global_load_lds(
      (const __attribute__((address_space(1))) void*)g,
      (__attribute__((address_space(3))) void*)l, 16, 0, 0);
}

__device__ __forceinline__ float sigmoidf_(float x) {
  return 1.0f / (1.0f + expf(-x));
}

// write-through f16 store: lands at the L3 coherence point, no dirty L2 line
__device__ __forceinline__ void st_f16_sc(f16* p, float v) {
  f16 h = (f16)v;
  unsigned u = (unsigned)__builtin_bit_cast(unsigned short, h);
  asm volatile("global_store_short %0, %1, off sc0 sc1"
               :: "v"(p), "v"(u) : "memory");
}

__device__ __forceinline__ unsigned ld_flag(const unsigned* p) {
  return __hip_atomic_load(p, __ATOMIC_RELAXED, __HIP_MEMORY_SCOPE_AGENT);
}
__device__ __forceinline__ void st_flag(unsigned* p, unsigned v) {
  __hip_atomic_store(p, v, __ATOMIC_RELAXED, __HIP_MEMORY_SCOPE_AGENT);
}

// ---------- transpose + cast: D[n][k] = (f16)S[k][n] ----------
__global__ __launch_bounds__(256) void k_transpose_f16(
    const float* __restrict__ S, f16* __restrict__ D, int K, int N) {
  __shared__ float tile[64][65];
  int nk = K >> 6;
  int k0 = (blockIdx.x % nk) << 6;
  int n0 = (blockIdx.x / nk) << 6;
  int tc = threadIdx.x & 63;
  int tq = threadIdx.x >> 6;
#pragma unroll
  for (int r = 0; r < 16; ++r) {
    int kk = tq * 16 + r;
    tile[kk][tc] = S[(size_t)(k0 + kk) * N + (n0 + tc)];
  }
  __syncthreads();
#pragma unroll
  for (int r = 0; r < 16; ++r) {
    int nn = tq * 16 + r;
    D[(size_t)(n0 + nn) * K + (k0 + tc)] = (f16)tile[tc][nn];
  }
}

// ---------- embedding lookup -> fp16 A0[m][512], row m = t*64 + b ----------
__global__ __launch_bounds__(256) void k_embed_f16(
    const int* __restrict__ tok, const float* __restrict__ emb,
    f16* __restrict__ A0) {
  int i = blockIdx.x * 256 + threadIdx.x;
  int m = i >> 7;
  int e = (i & 127) << 2;
  int t = m >> 6, b = m & 63;
  int tk = tok[b * 256 + t];
  const float4 v = *(const float4*)(emb + (size_t)tk * 512 + e);
  f16x4 o = {(f16)v.x, (f16)v.y, (f16)v.z, (f16)v.w};
  *(f16x4*)(A0 + (size_t)m * 512 + e) = o;
}

// ---------- C[m][n] = (f16)(sum_k A[m][k]*Bt[n][k] + bias[n]) ----------
__global__ __launch_bounds__(256) void k_gemm_f16(
    const f16* __restrict__ A, const f16* __restrict__ Bt,
    const float* __restrict__ bias, f16* __restrict__ C,
    int M, int N, int K) {
  __shared__ f16 sA[2][128 * 32];
  __shared__ f16 sB[2][128 * 32];
  const int tid = threadIdx.x, lane = tid & 63, w = tid >> 6;
  const int mb = M >> 7;
  const int bm = blockIdx.x % mb, bn = blockIdx.x / mb;
  const int am0 = bm << 7, bn0 = bn << 7;
  const int wm = w >> 1, wn = w & 1;
  const int srow = lane >> 2, sch = lane & 3;

  f32x4 acc[4][4] = {};
  const int NT = K >> 5;
  int cur = 0;

  auto stage = [&](int kt, int buf) {
#pragma unroll
    for (int q2 = 0; q2 < 2; ++q2) {
      int q = w * 2 + q2;
      int row = q * 16 + srow;
      const f16* ga = A + (size_t)(am0 + row) * K + kt * 32 + sch * 8;
      const f16* gb = Bt + (size_t)(bn0 + row) * K + kt * 32 + sch * 8;
      gl_lds16(ga, (char*)&sA[buf][0] + q * 1024);
      gl_lds16(gb, (char*)&sB[buf][0] + q * 1024);
    }
  };

  stage(0, 0);
  __syncthreads();
  for (int kt = 0; kt < NT; ++kt) {
    if (kt + 1 < NT) stage(kt + 1, cur ^ 1);
    const f16* pa = &sA[cur][(wm * 64 + (lane & 15)) * 32 + (lane >> 4) * 8];
    const f16* pb = &sB[cur][(wn * 64 + (lane & 15)) * 32 + (lane >> 4) * 8];
    f16x8 av[4], bv[4];
#pragma unroll
    for (int mf = 0; mf < 4; ++mf) av[mf] = *(const f16x8*)(pa + mf * 512);
#pragma unroll
    for (int nf = 0; nf < 4; ++nf) bv[nf] = *(const f16x8*)(pb + nf * 512);
#pragma unroll
    for (int mf = 0; mf < 4; ++mf)
#pragma unroll
      for (int nf = 0; nf < 4; ++nf)
        acc[mf][nf] = mfma16x32(av[mf], bv[nf], acc[mf][nf]);
    __syncthreads();
    cur ^= 1;
  }

#pragma unroll
  for (int mf = 0; mf < 4; ++mf)
#pragma unroll
    for (int nf = 0; nf < 4; ++nf) {
      int col = bn0 + wn * 64 + nf * 16 + (lane & 15);
      float bs = bias[col];
#pragma unroll
      for (int r = 0; r < 4; ++r) {
        int row = am0 + wm * 64 + mf * 16 + (lane >> 4) * 4 + r;
        C[(size_t)row * N + col] = (f16)(acc[mf][nf][r] + bs);
      }
    }
}

// ---------- batch-group persistent scan ----------
// bid decode: x=bid&7 (XCD), r=bid>>3; g=x>>1 (row group, 16 rows),
// l=r&1 (layer), cc=(x&1)*32+(r>>1) (col chunk: units [cc*16,cc*16+16),
// all 4 gates = 64 cols). Per group+layer: 64 blocks, own barrier.
// Wave w: K [w*256,w*256+256); 1 A-frag feeds 4 resident B-frags.
__global__ __launch_bounds__(256, 2) void k_scan5(
    const f16* __restrict__ XZ, const f16* __restrict__ U0t,
    const f16* __restrict__ W1t, const f16* __restrict__ U1t,
    const float* __restrict__ b1, f16* __restrict__ A1,
    f16* __restrict__ H1h, float* __restrict__ out, unsigned* arr,
    unsigned* rel, unsigned* mir) {
  __shared__ float zred[4224];  // 4 waves x 16 rows x stride 66
  const int tid = threadIdx.x, lane = tid & 63, w = tid >> 6;
  const int j = lane & 15, kg = lane >> 4;
  const int x = (int)blockIdx.x & 7, rb = (int)blockIdx.x >> 3;
  const int g = x >> 1, l = rb & 1;
  const int cc = ((x & 1) << 5) + (rb >> 1);
  const int grow0 = g * 16, u0c = cc * 16;
  unsigned* myArr = arr + (size_t)((g * 2 + l) * 64) * 32;
  unsigned* myRel = rel + (size_t)((g * 2 + l) * 64) * 32;
  unsigned* myMir = mir + (size_t)(g * 64) * 32;
  const int rr = tid >> 4, ul = tid & 15;
  const int erow = grow0 + rr, eu = u0c + ul;
  const int wko = w * 256 + kg * 8;
  const int aoff = (grow0 + j) * 1024 + wko;

  // resident weights: U0 (L0) or U1 (L1); asm-pinned against remat
  f16x8 bv[4][8];
  {
    const f16* WB = l ? U1t : U0t;
#pragma unroll
    for (int nf = 0; nf < 4; ++nf)
#pragma unroll
      for (int kt = 0; kt < 8; ++kt) {
        bv[nf][kt] =
            *(const f16x8*)(WB + (size_t)(nf * 1024 + u0c + j) * 1024 + wko +
                            kt * 32);
        asm volatile("" : "+v"(bv[nf][kt]));
      }
  }
  float c = 0.0f;  // this thread's (row, unit) cell state

  if (l == 0) {
    // ================= layer 0 =================
    float xz[4];
#pragma unroll
    for (int g4 = 0; g4 < 4; ++g4)
      xz[g4] = (float)XZ[(size_t)erow * 4096 + g4 * 1024 + eu];

    for (int s = 0; s < 256; ++s) {
      f32x4 acc[4] = {};
      if (s > 0) {
        const f16* ap = A1 + (size_t)(s - 1) * 65536 + aoff;
#pragma unroll
        for (int kt = 0; kt < 8; ++kt) {
          f16x8 av = *(const f16x8*)(ap + kt * 32);
#pragma unroll
          for (int nf = 0; nf < 4; ++nf)
            acc[nf] = mfma16x32(av, bv[nf][kt], acc[nf]);
        }
      }
#pragma unroll
      for (int nf = 0; nf < 4; ++nf)
#pragma unroll
        for (int q = 0; q < 4; ++q)
          zred[w * 1056 + (kg * 4 + q) * 66 + nf * 16 + j] = acc[nf][q];
      __syncthreads();
      float z[4];
#pragma unroll
      for (int g4 = 0; g4 < 4; ++g4) {
        float sm = xz[g4];
#pragma unroll
        for (int wv2 = 0; wv2 < 4; ++wv2)
          sm += zred[wv2 * 1056 + rr * 66 + g4 * 16 + ul];
        z[g4] = sm;
      }
      float gi = sigmoidf_(z[0]), gf = sigmoidf_(z[1]);
      float gg = tanhf(z[2]), go = sigmoidf_(z[3]);
      c = gf * c + gi * gg;
      st_f16_sc(&A1[(size_t)(s * 64 + erow) * 1024 + eu], go * tanhf(c));

      asm volatile("s_waitcnt vmcnt(0)" ::: "memory");
      float xzn[4] = {0.f, 0.f, 0.f, 0.f};
      if (s + 1 < 256) {
        const f16* xr = XZ + (size_t)((s + 1) * 64 + erow) * 4096;
#pragma unroll
        for (int g4 = 0; g4 < 4; ++g4) xzn[g4] = (float)xr[g4 * 1024 + eu];
      }
      __syncthreads();

      // group barrier0(s): afterwards group epoch = s+1
      const unsigned v = (unsigned)s + 1u;
      if (cc == 0) {
        if (tid >= 1 && tid < 64) {
          while (ld_flag(&myArr[(unsigned)tid * 32u]) < v)
            __builtin_amdgcn_s_sleep(1);
        }
        __syncthreads();
        if (tid >= 1 && tid < 64) st_flag(&myRel[(unsigned)tid * 32u], v);
        if (tid < 64) st_flag(&myMir[(unsigned)tid * 32u], v);
      } else {
        if (tid == 0) {
          st_flag(&myArr[(unsigned)cc * 32u], v);
          while (ld_flag(&myRel[(unsigned)cc * 32u]) < v)
            __builtin_amdgcn_s_sleep(1);
        }
        __syncthreads();
      }
#pragma unroll
      for (int g4 = 0; g4 < 4; ++g4) xz[g4] = xzn[g4];
    }
  } else {
    // ================= layer 1 =================
    float bias1[4];
#pragma unroll
    for (int g4 = 0; g4 < 4; ++g4) bias1[g4] = b1[g4 * 1024 + eu];

    // prime: wait group epoch 1; accW = W1 * h0(0)  (W1 streamed from L2)
    if (tid == 0) {
      while (ld_flag(&myMir[(unsigned)cc * 32u]) < 1u)
        __builtin_amdgcn_s_sleep(1);
    }
    __syncthreads();
    f32x4 accW[4] = {};
    {
      const f16* ap = A1 + aoff;
#pragma unroll
      for (int kt = 0; kt < 8; ++kt) {
        f16x8 av = *(const f16x8*)(ap + kt * 32);
#pragma unroll
        for (int nf = 0; nf < 4; ++nf) {
          f16x8 wv =
              *(const f16x8*)(W1t + (size_t)(nf * 1024 + u0c + j) * 1024 +
                              wko + kt * 32);
          accW[nf] = mfma16x32(av, wv, accW[nf]);
        }
      }
    }

    for (int t = 0; t < 256; ++t) {
      f32x4 acc[4] = {accW[0], accW[1], accW[2], accW[3]};
      if (t > 0) {
        const f16* hp = H1h + (size_t)(t - 1) * 65536 + aoff;
#pragma unroll
        for (int kt = 0; kt < 8; ++kt) {
          f16x8 av = *(const f16x8*)(hp + kt * 32);
#pragma unroll
          for (int nf = 0; nf < 4; ++nf)
            acc[nf] = mfma16x32(av, bv[nf][kt], acc[nf]);
        }
      }
#pragma unroll
      for (int nf = 0; nf < 4; ++nf)
#pragma unroll
        for (int q = 0; q < 4; ++q)
          zred[w * 1056 + (kg * 4 + q) * 66 + nf * 16 + j] = acc[nf][q];
      __syncthreads();
      float z[4];
#pragma unroll
      for (int g4 = 0; g4 < 4; ++g4) {
        float sm = bias1[g4];
#pragma unroll
        for (int wv2 = 0; wv2 < 4; ++wv2)
          sm += zred[wv2 * 1056 + rr * 66 + g4 * 16 + ul];
        z[g4] = sm;
      }
      float gi = sigmoidf_(z[0]), gf = sigmoidf_(z[1]);
      float gg = tanhf(z[2]), go = sigmoidf_(z[3]);
      c = gf * c + gi * gg;
      float hn = go * tanhf(c);
      if (t == 255) {
        out[(size_t)erow * 262144 + (size_t)t * 1024 + eu] = hn;
        out[16777216 + erow * 1024 + eu] = hn;
        out[16777216 + 65536 + erow * 1024 + eu] = c;
        break;  // last step: no publish/barrier
      }
      st_f16_sc(&H1h[(size_t)t * 65536 + erow * 1024 + eu], hn);

      asm volatile("s_waitcnt vmcnt(0)" ::: "memory");
      __syncthreads();
      const unsigned v = (unsigned)t + 1u;
      if (cc == 0) {
        if (tid >= 1 && tid < 64) {
          while (ld_flag(&myArr[(unsigned)tid * 32u]) < v)
            __builtin_amdgcn_s_sleep(1);
        }
        __syncthreads();
        if (tid >= 1 && tid < 64) st_flag(&myRel[(unsigned)tid * 32u], v);
      } else {
        if (tid == 0) st_flag(&myArr[(unsigned)cc * 32u], v);
      }
      // deferred out store: hides under the epoch/release waits
      out[(size_t)erow * 262144 + (size_t)t * 1024 + eu] = hn;
      // overlap: next step's W1 pass, gated on group epoch t+2
      if (tid == 0) {
        while (ld_flag(&myMir[(unsigned)cc * 32u]) < v + 1u)
          __builtin_amdgcn_s_sleep(1);
      }
      __syncthreads();
      {
        const f16* ap = A1 + (size_t)(t + 1) * 65536 + aoff;
        f32x4 tw[4] = {};
#pragma unroll
        for (int kt = 0; kt < 8; ++kt) {
          f16x8 av = *(const f16x8*)(ap + kt * 32);
#pragma unroll
          for (int nf = 0; nf < 4; ++nf) {
            f16x8 wv =
                *(const f16x8*)(W1t + (size_t)(nf * 1024 + u0c + j) * 1024 +
                                wko + kt * 32);
            tw[nf] = mfma16x32(av, wv, tw[nf]);
          }
        }
#pragma unroll
        for (int nf = 0; nf < 4; ++nf) accW[nf] = tw[nf];
      }
      if (cc != 0) {
        if (tid == 0) {
          while (ld_flag(&myRel[(unsigned)cc * 32u]) < v)
            __builtin_amdgcn_s_sleep(1);
        }
        __syncthreads();
      }
    }
  }
}

// ---------- fallback: fused per-step kernel (r10, proven) ----------
__device__ __forceinline__ void reduce4(const f32x4 acc[4], float* zred,
                                        float z[4]) {
  const int tid = threadIdx.x, lane = tid & 63, w = tid >> 6;
  const int j = lane & 15, kg = lane >> 4;
#pragma unroll
  for (int mf = 0; mf < 4; ++mf)
#pragma unroll
    for (int r = 0; r < 4; ++r)
      zred[w * 1088 + (mf * 16 + kg * 4 + r) * 17 + j] = acc[mf][r];
  __syncthreads();
  const int erow = tid >> 2, euu = tid & 3;
#pragma unroll
  for (int g = 0; g < 4; ++g) {
#pragma unroll
    for (int wv = 0; wv < 4; ++wv)
      z[g] += zred[wv * 1088 + erow * 17 + g * 4 + euu];
  }
}

__device__ __forceinline__ void step_once(
    int s, int u0, const f16x8 bvU0[8], const f16x8 bvW1[8],
    const f16x8 bvU1[8], const float bias1[4], const float xz[4],
    f16* __restrict__ A1, f16* __restrict__ H1h, int hmask,
    float& c0, float& c1, float* __restrict__ out, float* zred) {
  const int tid = threadIdx.x, lane = tid & 63, w = tid >> 6;
  const int j = lane & 15, kg = lane >> 4;
  const int aoff = j * 1024 + w * 256 + kg * 8;
  const int erow = tid >> 2;
  const int eu = u0 + (tid & 3);

  f32x4 accA[4] = {};
  f32x4 accB[4] = {};

  if (s >= 1) {
    const f16* ap = A1 + (size_t)(s - 1) * 65536 + aoff;
#pragma unroll
    for (int kt = 0; kt < 8; ++kt)
#pragma unroll
      for (int mf = 0; mf < 4; ++mf) {
        f16x8 av = *(const f16x8*)(ap + mf * 16384 + kt * 32);
        if (s < 256) accA[mf] = mfma16x32(av, bvU0[kt], accA[mf]);
        accB[mf] = mfma16x32(av, bvW1[kt], accB[mf]);
      }
    if (s >= 2) {
      const f16* hp = H1h + (size_t)((s - 2) & hmask) * 65536 + aoff;
#pragma unroll
      for (int kt = 0; kt < 8; ++kt)
#pragma unroll
        for (int mf = 0; mf < 4; ++mf)
          accB[mf] = mfma16x32(*(const f16x8*)(hp + mf * 16384 + kt * 32),
                               bvU1[kt], accB[mf]);
    }
  }

  if (s < 256) {
    float z[4] = {xz[0], xz[1], xz[2], xz[3]};
    reduce4(accA, zred, z);
    float gi = sigmoidf_(z[0]), gf = sigmoidf_(z[1]);
    float gg = tanhf(z[2]), go = sigmoidf_(z[3]);
    c0 = gf * c0 + gi * gg;
    st_f16_sc(&A1[(size_t)(s * 64 + erow) * 1024 + eu], go * tanhf(c0));
  }
  __syncthreads();

  if (s >= 1) {
    const int t = s - 1;
    float z[4] = {bias1[0], bias1[1], bias1[2], bias1[3]};
    reduce4(accB, zred, z);
    float gi = sigmoidf_(z[0]), gf = sigmoidf_(z[1]);
    float gg = tanhf(z[2]), go = sigmoidf_(z[3]);
    c1 = gf * c1 + gi * gg;
    float hn = go * tanhf(c1);
    st_f16_sc(&H1h[(size_t)(t & hmask) * 65536 + erow * 1024 + eu], hn);
    out[(size_t)erow * 262144 + (size_t)t * 1024 + eu] = hn;
    if (t == 255) {
      out[16777216 + erow * 1024 + eu] = hn;
      out[16777216 + 65536 + erow * 1024 + eu] = c1;
    }
  }
}

__global__ __launch_bounds__(256, 1) void k_step(
    const f16* __restrict__ XZ, const f16* __restrict__ U0t,
    const f16* __restrict__ W1t, const f16* __restrict__ U1t,
    const float* __restrict__ b1, f16* __restrict__ A1,
    f16* __restrict__ H1h, float* __restrict__ C0, float* __restrict__ C1,
    float* __restrict__ out, int s) {
  __shared__ float zred[4352];
  const int tid_ = threadIdx.x, lane_ = tid_ & 63, w_ = tid_ >> 6;
  const int bid_ = (int)blockIdx.x;
  const int i_ = ((bid_ & 7) << 5) + (bid_ >> 3);
  const int u0 = i_ * 4;
  const int j_ = lane_ & 15;
  const int kg_ = lane_ >> 4;
  const int ncol_ = (j_ >> 2) * 1024 + u0 + (j_ & 3);
  const int woff_ = ncol_ * 1024 + w_ * 256 + kg_ * 8;
  f16x8 bvU0[8], bvW1[8], bvU1[8];
#pragma unroll
  for (int kt = 0; kt < 8; ++kt) {
    bvU0[kt] = *(const f16x8*)(U0t + woff_ + kt * 32);
    bvW1[kt] = *(const f16x8*)(W1t + woff_ + kt * 32);
    bvU1[kt] = *(const f16x8*)(U1t + woff_ + kt * 32);
  }
  const int erow_ = tid_ >> 2;
  const int eu_ = u0 + (tid_ & 3);
  float bias1[4];
#pragma unroll
  for (int g = 0; g < 4; ++g) bias1[g] = b1[g * 1024 + eu_];

  float xz[4] = {0.f, 0.f, 0.f, 0.f};
  if (s < 256) {
    const f16* xrow = XZ + (size_t)(s * 64 + erow_) * 4096;
#pragma unroll
    for (int g = 0; g < 4; ++g) xz[g] = (float)xrow[g * 1024 + eu_];
  }
  float c0 = C0[erow_ * 1024 + eu_];
  float c1 = C1[erow_ * 1024 + eu_];
  step_once(s, u0, bvU0, bvW1, bvU1, bias1, xz, A1, H1h, 1, c0, c1, out,
            zred);
  C0[erow_ * 1024 + eu_] = c0;
  C1[erow_ * 1024 + eu_] = c1;
}

extern "C" void kernel_launch(void* const* d_in, const int* in_sizes, int n_in,
                              void* d_out, int out_size, void* d_ws, size_t ws_size,
                              hipStream_t stream) {
  (void)in_sizes; (void)n_in; (void)out_size;
  const int* tokens = (const int*)d_in[0];
  const float* emb = (const float*)d_in[1];
  const float* W0 = (const float*)d_in[2];
  const float* U0 = (const float*)d_in[3];
  const float* b0 = (const float*)d_in[4];
  const float* W1 = (const float*)d_in[5];
  const float* U1 = (const float*)d_in[6];
  const float* b1 = (const float*)d_in[7];
  float* out = (float*)d_out;

  // workspace carve-up; H1h LAST (coop path needs the full 256 slots)
  char* p = (char*)d_ws;
  f16* A0 = (f16*)p;   p += (size_t)16384 * 512 * 2;    // x tokens, fp16
  f16* A1 = (f16*)p;   p += (size_t)16384 * 1024 * 2;   // h0 history
  f16* W0t = (f16*)p;  p += (size_t)4096 * 512 * 2;     // W0^T
  f16* U0t = (f16*)p;  p += (size_t)4096 * 1024 * 2;    // U0^T
  f16* W1t = (f16*)p;  p += (size_t)4096 * 1024 * 2;    // W1^T
  f16* U1t = (f16*)p;  p += (size_t)4096 * 1024 * 2;    // U1^T
  f16* XZ = (f16*)p;   p += (size_t)16384 * 4096 * 2;   // xz0, rows t*64+b
  float* C0 = (float*)p; p += 64 * 1024 * 4;            // cell L0 (fallback)
  float* C1 = (float*)p; p += 64 * 1024 * 4;            // cell L1 (fallback)
  unsigned* arr = (unsigned*)p; p += 8 * 64 * 32 * 4;   // arrive lines (g,l)
  unsigned* rel = (unsigned*)p; p += 8 * 64 * 32 * 4;   // release lines
  unsigned* mir = (unsigned*)p; p += 4 * 64 * 32 * 4;   // epoch mirrors (g)
  f16* H1h = (f16*)p;                                   // h1 history slots
  const size_t need_coop = (size_t)(p - (char*)d_ws) + (size_t)256 * 65536 * 2;

  // weight transposes + casts
  k_transpose_f16<<<512, 256, 0, stream>>>(W0, W0t, 512, 4096);
  k_transpose_f16<<<1024, 256, 0, stream>>>(U0, U0t, 1024, 4096);
  k_transpose_f16<<<1024, 256, 0, stream>>>(W1, W1t, 1024, 4096);
  k_transpose_f16<<<1024, 256, 0, stream>>>(U1, U1t, 1024, 4096);

  // embedding
  k_embed_f16<<<8192, 256, 0, stream>>>(tokens, emb, A0);

  // layer 0 input projection: xz0 = x @ W0 + b0
  k_gemm_f16<<<4096, 256, 0, stream>>>(A0, W0t, b0, XZ, 16384, 4096, 512);

  hipMemsetAsync(C0, 0, 64 * 1024 * 4 * 2, stream);        // C0+C1
  hipMemsetAsync(arr, 0, (8 + 8 + 4) * 64 * 32 * 4, stream);  // flags

  bool coop_ok = (ws_size >= need_coop);
  if (coop_ok) {
    const f16* XZc = XZ; const f16* U0c = U0t; const f16* W1c = W1t;
    const f16* U1c = U1t; const float* b1c = b1;
    f16* A1p = A1; f16* H1p = H1h; float* outp = out;
    unsigned* ar = arr; unsigned* rl = rel; unsigned* mr = mir;
    void* kargs[] = {(void*)&XZc, (void*)&U0c, (void*)&W1c, (void*)&U1c,
                     (void*)&b1c, (void*)&A1p, (void*)&H1p, (void*)&outp,
                     (void*)&ar, (void*)&rl, (void*)&mr};
    hipError_t e = hipLaunchCooperativeKernel((const void*)k_scan5, dim3(512),
                                              dim3(256), kargs, 0, stream);
    if (e != hipSuccess) {
      (void)hipGetLastError();
      coop_ok = false;
    }
  }
  if (!coop_ok) {
    for (int s = 0; s <= 256; ++s)
      k_step<<<256, 256, 0, stream>>>(XZ, U0t, W1t, U1t, b1, A1, H1h, C0, C1,
                                      out, s);
  }
}

// Round 12
// 2415.998 us; speedup vs baseline: 1.3023x; 1.3023x over previous
//
#include <hip/hip_runtime.h>

// LSTM encoder: V=32000 E=512 U=1024 L=2, B=64 T=256.
// Round 12: r10 structure (decoupled L0/L1 barriers, dual-B-frag batch-split
// blocks, XCD swizzle) + FORCED weight residency. r10's VGPR=108 proved the
// compiler rematerialized weight fragments as per-step L2 reloads (U1 reload
// on the critical pass); r11 proved streaming W1 thrashes L2 (FETCH 2x).
// asm-pin makes U0/W1/U1 truly VGPR-resident. zred stride 18 (write conflict
// 4-way -> 2-way = free); out store deferred past the arrive flag.

typedef _Float16 f16;
typedef _Float16 f16x8 __attribute__((ext_vector_type(8)));
typedef _Float16 f16x4 __attribute__((ext_vector_type(4)));
typedef float f32x4 __attribute__((ext_vector_type(4)));

__device__ __forceinline__ f32x4 mfma16x32(f16x8 a, f16x8 b, f32x4 c) {
  return __builtin_amdgcn_mfma_f32_16x16x32_f16(a, b, c, 0, 0, 0);
}

__device__ __forceinline__ void gl_lds16(const void* g, void* l) {
  __builtin_amdgcn_global_load_lds(
      (const __attribute__((address_space(1))) void*)g,
      (__attribute__((address_space(3))) void*)l, 16, 0, 0);
}

__device__ __forceinline__ float sigmoidf_(float x) {
  return 1.0f / (1.0f + expf(-x));
}

// write-through f16 store: lands at the L3 coherence point, no dirty L2 line
__device__ __forceinline__ void st_f16_sc(f16* p, float v) {
  f16 h = (f16)v;
  unsigned u = (unsigned)__builtin_bit_cast(unsigned short, h);
  asm volatile("global_store_short %0, %1, off sc0 sc1"
               :: "v"(p), "v"(u) : "memory");
}

__device__ __forceinline__ unsigned ld_flag(const unsigned* p) {
  return __hip_atomic_load(p, __ATOMIC_RELAXED, __HIP_MEMORY_SCOPE_AGENT);
}
__device__ __forceinline__ void st_flag(unsigned* p, unsigned v) {
  __hip_atomic_store(p, v, __ATOMIC_RELAXED, __HIP_MEMORY_SCOPE_AGENT);
}

// ---------- transpose + cast: D[n][k] = (f16)S[k][n] ----------
__global__ __launch_bounds__(256) void k_transpose_f16(
    const float* __restrict__ S, f16* __restrict__ D, int K, int N) {
  __shared__ float tile[64][65];
  int nk = K >> 6;
  int k0 = (blockIdx.x % nk) << 6;
  int n0 = (blockIdx.x / nk) << 6;
  int tc = threadIdx.x & 63;
  int tq = threadIdx.x >> 6;
#pragma unroll
  for (int r = 0; r < 16; ++r) {
    int kk = tq * 16 + r;
    tile[kk][tc] = S[(size_t)(k0 + kk) * N + (n0 + tc)];
  }
  __syncthreads();
#pragma unroll
  for (int r = 0; r < 16; ++r) {
    int nn = tq * 16 + r;
    D[(size_t)(n0 + nn) * K + (k0 + tc)] = (f16)tile[tc][nn];
  }
}

// ---------- embedding lookup -> fp16 A0[m][512], row m = t*64 + b ----------
__global__ __launch_bounds__(256) void k_embed_f16(
    const int* __restrict__ tok, const float* __restrict__ emb,
    f16* __restrict__ A0) {
  int i = blockIdx.x * 256 + threadIdx.x;
  int m = i >> 7;
  int e = (i & 127) << 2;
  int t = m >> 6, b = m & 63;
  int tk = tok[b * 256 + t];
  const float4 v = *(const float4*)(emb + (size_t)tk * 512 + e);
  f16x4 o = {(f16)v.x, (f16)v.y, (f16)v.z, (f16)v.w};
  *(f16x4*)(A0 + (size_t)m * 512 + e) = o;
}

// ---------- C[m][n] = (f16)(sum_k A[m][k]*Bt[n][k] + bias[n]) ----------
__global__ __launch_bounds__(256) void k_gemm_f16(
    const f16* __restrict__ A, const f16* __restrict__ Bt,
    const float* __restrict__ bias, f16* __restrict__ C,
    int M, int N, int K) {
  __shared__ f16 sA[2][128 * 32];
  __shared__ f16 sB[2][128 * 32];
  const int tid = threadIdx.x, lane = tid & 63, w = tid >> 6;
  const int mb = M >> 7;
  const int bm = blockIdx.x % mb, bn = blockIdx.x / mb;
  const int am0 = bm << 7, bn0 = bn << 7;
  const int wm = w >> 1, wn = w & 1;
  const int srow = lane >> 2, sch = lane & 3;

  f32x4 acc[4][4] = {};
  const int NT = K >> 5;
  int cur = 0;

  auto stage = [&](int kt, int buf) {
#pragma unroll
    for (int q2 = 0; q2 < 2; ++q2) {
      int q = w * 2 + q2;
      int row = q * 16 + srow;
      const f16* ga = A + (size_t)(am0 + row) * K + kt * 32 + sch * 8;
      const f16* gb = Bt + (size_t)(bn0 + row) * K + kt * 32 + sch * 8;
      gl_lds16(ga, (char*)&sA[buf][0] + q * 1024);
      gl_lds16(gb, (char*)&sB[buf][0] + q * 1024);
    }
  };

  stage(0, 0);
  __syncthreads();
  for (int kt = 0; kt < NT; ++kt) {
    if (kt + 1 < NT) stage(kt + 1, cur ^ 1);
    const f16* pa = &sA[cur][(wm * 64 + (lane & 15)) * 32 + (lane >> 4) * 8];
    const f16* pb = &sB[cur][(wn * 64 + (lane & 15)) * 32 + (lane >> 4) * 8];
    f16x8 av[4], bv[4];
#pragma unroll
    for (int mf = 0; mf < 4; ++mf) av[mf] = *(const f16x8*)(pa + mf * 512);
#pragma unroll
    for (int nf = 0; nf < 4; ++nf) bv[nf] = *(const f16x8*)(pb + nf * 512);
#pragma unroll
    for (int mf = 0; mf < 4; ++mf)
#pragma unroll
      for (int nf = 0; nf < 4; ++nf)
        acc[mf][nf] = mfma16x32(av[mf], bv[nf], acc[mf][nf]);
    __syncthreads();
    cur ^= 1;
  }

#pragma unroll
  for (int mf = 0; mf < 4; ++mf)
#pragma unroll
    for (int nf = 0; nf < 4; ++nf) {
      int col = bn0 + wn * 64 + nf * 16 + (lane & 15);
      float bs = bias[col];
#pragma unroll
      for (int r = 0; r < 4; ++r) {
        int row = am0 + wm * 64 + mf * 16 + (lane >> 4) * 4 + r;
        C[(size_t)row * N + col] = (f16)(acc[mf][nf][r] + bs);
      }
    }
}

// ---------- decoupled scan, dual-B-frag + batch-split, pinned weights ----------
// 512 blocks x 256 thr. bid<256: L0; else L1. rb=0..255 per layer:
//   ug = (rb&7)*16 + (rb>>3)&15  (unit-group, 8 units; XCD-local)
//   rh = rb>>7                   (batch half: rows rh*32..rh*32+32)
// Wave w: K-chunk w*256; dual 16-col weight sets (units u0..u0+4 / +4..+8).
__global__ __launch_bounds__(256, 2) void k_scan6(
    const f16* __restrict__ XZ, const f16* __restrict__ U0t,
    const f16* __restrict__ W1t, const f16* __restrict__ U1t,
    const float* __restrict__ b1, f16* __restrict__ A1,
    f16* __restrict__ H1h, float* __restrict__ out, unsigned* arr0,
    unsigned* rel0, unsigned* arr1, unsigned* rel1, unsigned* mir) {
  __shared__ float zred[4608];  // 2 sets x 4 waves x 32 rows x stride 18
  const int tid = threadIdx.x, lane = tid & 63, w = tid >> 6;
  const bool isL1 = (blockIdx.x >= 256);
  const int rb = isL1 ? (int)blockIdx.x - 256 : (int)blockIdx.x;
  const int ug = ((rb & 7) << 4) + ((rb >> 3) & 15);
  const int rh = rb >> 7;
  const int u0 = ug * 8;
  const int j = lane & 15, kg = lane >> 4;
  const int aoff = (rh * 32 + j) * 1024 + w * 256 + kg * 8;
  // epilogue: one (row, unit) per thread
  const int erl = tid >> 3;                   // local row 0..31
  const int eunit = tid & 7;
  const int q_e = eunit >> 2, euu = eunit & 3;
  const int erow = rh * 32 + erl;
  const int eu = u0 + eunit;

  // dual weight sets per wave -- asm-pinned so they stay in VGPRs
  const int wo0 = ((j >> 2) * 1024 + u0 + (j & 3)) * 1024 + w * 256 + kg * 8;
  const int wo1 = wo0 + 4 * 1024;
  f16x8 bA0[8], bA1[8], bB0[8], bB1[8];
  {
    const f16* base = isL1 ? W1t : U0t;
#pragma unroll
    for (int kt = 0; kt < 8; ++kt) {
      bA0[kt] = *(const f16x8*)(base + wo0 + kt * 32);
      bA1[kt] = *(const f16x8*)(base + wo1 + kt * 32);
      asm volatile("" : "+v"(bA0[kt]), "+v"(bA1[kt]));
    }
  }
  if (isL1) {
#pragma unroll
    for (int kt = 0; kt < 8; ++kt) {
      bB0[kt] = *(const f16x8*)(U1t + wo0 + kt * 32);
      bB1[kt] = *(const f16x8*)(U1t + wo1 + kt * 32);
      asm volatile("" : "+v"(bB0[kt]), "+v"(bB1[kt]));
    }
  }
  float c = 0.0f;  // this thread's (row,unit) cell state

  if (!isL1) {
    // ================= layer 0 =================
    float xz[4];
#pragma unroll
    for (int g = 0; g < 4; ++g)
      xz[g] = (float)XZ[(size_t)erow * 4096 + g * 1024 + eu];

    for (int s = 0; s < 256; ++s) {
      f32x4 a0[2] = {}, a1[2] = {};
      if (s > 0) {
        const f16* ap = A1 + (size_t)(s - 1) * 65536 + aoff;
#pragma unroll
        for (int kt = 0; kt < 8; ++kt)
#pragma unroll
          for (int mf = 0; mf < 2; ++mf) {
            f16x8 av = *(const f16x8*)(ap + mf * 16384 + kt * 32);
            a0[mf] = mfma16x32(av, bA0[kt], a0[mf]);
            a1[mf] = mfma16x32(av, bA1[kt], a1[mf]);
          }
      }
#pragma unroll
      for (int mf = 0; mf < 2; ++mf)
#pragma unroll
        for (int r = 0; r < 4; ++r) {
          zred[w * 576 + (mf * 16 + kg * 4 + r) * 18 + j] = a0[mf][r];
          zred[2304 + w * 576 + (mf * 16 + kg * 4 + r) * 18 + j] = a1[mf][r];
        }
      __syncthreads();
      float z[4];
#pragma unroll
      for (int g = 0; g < 4; ++g) {
        float sm = xz[g];
#pragma unroll
        for (int wv = 0; wv < 4; ++wv)
          sm += zred[q_e * 2304 + wv * 576 + erl * 18 + g * 4 + euu];
        z[g] = sm;
      }
      float gi = sigmoidf_(z[0]), gf = sigmoidf_(z[1]);
      float gg = tanhf(z[2]), go = sigmoidf_(z[3]);
      c = gf * c + gi * gg;
      st_f16_sc(&A1[(size_t)(s * 64 + erow) * 1024 + eu], go * tanhf(c));

      // drain stores, then prefetch next xz (completes under barrier wait)
      asm volatile("s_waitcnt vmcnt(0)" ::: "memory");
      float xzn[4] = {0.f, 0.f, 0.f, 0.f};
      if (s + 1 < 256) {
        const f16* xrow = XZ + (size_t)((s + 1) * 64 + erow) * 4096;
#pragma unroll
        for (int g = 0; g < 4; ++g) xzn[g] = (float)xrow[g * 1024 + eu];
      }
      __syncthreads();

      // barrier0(s); afterwards epoch = s+1 (A1[0..s] visible)
      const unsigned v = (unsigned)s + 1u;
      if (rb == 0) {
        if (tid > 0) {
          while (ld_flag(&arr0[(unsigned)tid * 32u]) < v)
            __builtin_amdgcn_s_sleep(1);
        }
        __syncthreads();  // all 255 arrivals observed
        if (tid > 0) st_flag(&rel0[(unsigned)tid * 32u], v);
        st_flag(&mir[(unsigned)tid * 32u], v);  // epoch to every L1 block
      } else {
        if (tid == 0) {
          st_flag(&arr0[(unsigned)rb * 32u], v);
          while (ld_flag(&rel0[(unsigned)rb * 32u]) < v)
            __builtin_amdgcn_s_sleep(1);
        }
        __syncthreads();
      }
#pragma unroll
      for (int g = 0; g < 4; ++g) xz[g] = xzn[g];
    }
  } else {
    // ================= layer 1 =================
    float bias1[4];
#pragma unroll
    for (int g = 0; g < 4; ++g) bias1[g] = b1[g * 1024 + eu];

    // prime: wait epoch 1, compute accW = W1 * h0(0)
    if (tid == 0) {
      while (ld_flag(&mir[(unsigned)rb * 32u]) < 1u)
        __builtin_amdgcn_s_sleep(1);
    }
    __syncthreads();
    f32x4 accW0[2] = {}, accW1[2] = {};
    {
      const f16* ap = A1 + aoff;
#pragma unroll
      for (int kt = 0; kt < 8; ++kt)
#pragma unroll
        for (int mf = 0; mf < 2; ++mf) {
          f16x8 av = *(const f16x8*)(ap + mf * 16384 + kt * 32);
          accW0[mf] = mfma16x32(av, bA0[kt], accW0[mf]);
          accW1[mf] = mfma16x32(av, bA1[kt], accW1[mf]);
        }
    }

    for (int t = 0; t < 256; ++t) {
      f32x4 a0[2] = {accW0[0], accW0[1]};
      f32x4 a1[2] = {accW1[0], accW1[1]};
      if (t > 0) {
        const f16* hp = H1h + (size_t)(t - 1) * 65536 + aoff;
#pragma unroll
        for (int kt = 0; kt < 8; ++kt)
#pragma unroll
          for (int mf = 0; mf < 2; ++mf) {
            f16x8 av = *(const f16x8*)(hp + mf * 16384 + kt * 32);
            a0[mf] = mfma16x32(av, bB0[kt], a0[mf]);
            a1[mf] = mfma16x32(av, bB1[kt], a1[mf]);
          }
      }
#pragma unroll
      for (int mf = 0; mf < 2; ++mf)
#pragma unroll
        for (int r = 0; r < 4; ++r) {
          zred[w * 576 + (mf * 16 + kg * 4 + r) * 18 + j] = a0[mf][r];
          zred[2304 + w * 576 + (mf * 16 + kg * 4 + r) * 18 + j] = a1[mf][r];
        }
      __syncthreads();
      float z[4];
#pragma unroll
      for (int g = 0; g < 4; ++g) {
        float sm = bias1[g];
#pragma unroll
        for (int wv = 0; wv < 4; ++wv)
          sm += zred[q_e * 2304 + wv * 576 + erl * 18 + g * 4 + euu];
        z[g] = sm;
      }
      float gi = sigmoidf_(z[0]), gf = sigmoidf_(z[1]);
      float gg = tanhf(z[2]), go = sigmoidf_(z[3]);
      c = gf * c + gi * gg;
      float hn = go * tanhf(c);
      if (t == 255) {
        out[(size_t)erow * 262144 + (size_t)t * 1024 + eu] = hn;
        out[16777216 + erow * 1024 + eu] = hn;
        out[16777216 + 65536 + erow * 1024 + eu] = c;
        break;  // last step: no publish/barrier needed
      }
      st_f16_sc(&H1h[(size_t)t * 65536 + erow * 1024 + eu], hn);

      // barrier1(t) with W1-pass overlap in the wait window
      asm volatile("s_waitcnt vmcnt(0)" ::: "memory");
      __syncthreads();
      const unsigned v = (unsigned)t + 1u;
      if (rb == 0) {
        // leader: gather + release FIRST so workers aren't held up
        if (tid > 0) {
          while (ld_flag(&arr1[(unsigned)tid * 32u]) < v)
            __builtin_amdgcn_s_sleep(1);
        }
        __syncthreads();
        if (tid > 0) st_flag(&rel1[(unsigned)tid * 32u], v);
      } else {
        if (tid == 0) st_flag(&arr1[(unsigned)rb * 32u], v);
      }
      // deferred out store: hides under the epoch/release waits
      out[(size_t)erow * 262144 + (size_t)t * 1024 + eu] = hn;
      // overlap: next step's W1 pass, gated on epoch t+2
      if (tid == 0) {
        while (ld_flag(&mir[(unsigned)rb * 32u]) < v + 1u)
          __builtin_amdgcn_s_sleep(1);
      }
      __syncthreads();
      {
        const f16* ap = A1 + (size_t)(t + 1) * 65536 + aoff;
        f32x4 t0[2] = {}, t1[2] = {};
#pragma unroll
        for (int kt = 0; kt < 8; ++kt)
#pragma unroll
          for (int mf = 0; mf < 2; ++mf) {
            f16x8 av = *(const f16x8*)(ap + mf * 16384 + kt * 32);
            t0[mf] = mfma16x32(av, bA0[kt], t0[mf]);
            t1[mf] = mfma16x32(av, bA1[kt], t1[mf]);
          }
#pragma unroll
        for (int mf = 0; mf < 2; ++mf) {
          accW0[mf] = t0[mf];
          accW1[mf] = t1[mf];
        }
      }
      // wait for release (workers; leader already released)
      if (rb != 0) {
        if (tid == 0) {
          while (ld_flag(&rel1[(unsigned)rb * 32u]) < v)
            __builtin_amdgcn_s_sleep(1);
        }
        __syncthreads();
      }
    }
  }
}

// ---------- fallback: fused per-step kernel (r9/r10, proven) ----------
__device__ __forceinline__ void reduce4(const f32x4 acc[4], float* zred,
                                        float z[4]) {
  const int tid = threadIdx.x, lane = tid & 63, w = tid >> 6;
  const int j = lane & 15, kg = lane >> 4;
#pragma unroll
  for (int mf = 0; mf < 4; ++mf)
#pragma unroll
    for (int r = 0; r < 4; ++r)
      zred[w * 1088 + (mf * 16 + kg * 4 + r) * 17 + j] = acc[mf][r];
  __syncthreads();
  const int erow = tid >> 2, euu = tid & 3;
#pragma unroll
  for (int g = 0; g < 4; ++g) {
#pragma unroll
    for (int wv = 0; wv < 4; ++wv)
      z[g] += zred[wv * 1088 + erow * 17 + g * 4 + euu];
  }
}

__device__ __forceinline__ void step_once(
    int s, int u0, const f16x8 bvU0[8], const f16x8 bvW1[8],
    const f16x8 bvU1[8], const float bias1[4], const float xz[4],
    f16* __restrict__ A1, f16* __restrict__ H1h, int hmask,
    float& c0, float& c1, float* __restrict__ out, float* zred) {
  const int tid = threadIdx.x, lane = tid & 63, w = tid >> 6;
  const int j = lane & 15, kg = lane >> 4;
  const int aoff = j * 1024 + w * 256 + kg * 8;
  const int erow = tid >> 2;
  const int eu = u0 + (tid & 3);

  f32x4 accA[4] = {};
  f32x4 accB[4] = {};

  if (s >= 1) {
    const f16* ap = A1 + (size_t)(s - 1) * 65536 + aoff;
#pragma unroll
    for (int kt = 0; kt < 8; ++kt)
#pragma unroll
      for (int mf = 0; mf < 4; ++mf) {
        f16x8 av = *(const f16x8*)(ap + mf * 16384 + kt * 32);
        if (s < 256) accA[mf] = mfma16x32(av, bvU0[kt], accA[mf]);
        accB[mf] = mfma16x32(av, bvW1[kt], accB[mf]);
      }
    if (s >= 2) {
      const f16* hp = H1h + (size_t)((s - 2) & hmask) * 65536 + aoff;
#pragma unroll
      for (int kt = 0; kt < 8; ++kt)
#pragma unroll
        for (int mf = 0; mf < 4; ++mf)
          accB[mf] = mfma16x32(*(const f16x8*)(hp + mf * 16384 + kt * 32),
                               bvU1[kt], accB[mf]);
    }
  }

  if (s < 256) {
    float z[4] = {xz[0], xz[1], xz[2], xz[3]};
    reduce4(accA, zred, z);
    float gi = sigmoidf_(z[0]), gf = sigmoidf_(z[1]);
    float gg = tanhf(z[2]), go = sigmoidf_(z[3]);
    c0 = gf * c0 + gi * gg;
    st_f16_sc(&A1[(size_t)(s * 64 + erow) * 1024 + eu], go * tanhf(c0));
  }
  __syncthreads();

  if (s >= 1) {
    const int t = s - 1;
    float z[4] = {bias1[0], bias1[1], bias1[2], bias1[3]};
    reduce4(accB, zred, z);
    float gi = sigmoidf_(z[0]), gf = sigmoidf_(z[1]);
    float gg = tanhf(z[2]), go = sigmoidf_(z[3]);
    c1 = gf * c1 + gi * gg;
    float hn = go * tanhf(c1);
    st_f16_sc(&H1h[(size_t)(t & hmask) * 65536 + erow * 1024 + eu], hn);
    out[(size_t)erow * 262144 + (size_t)t * 1024 + eu] = hn;
    if (t == 255) {
      out[16777216 + erow * 1024 + eu] = hn;
      out[16777216 + 65536 + erow * 1024 + eu] = c1;
    }
  }
}

__global__ __launch_bounds__(256, 1) void k_step(
    const f16* __restrict__ XZ, const f16* __restrict__ U0t,
    const f16* __restrict__ W1t, const f16* __restrict__ U1t,
    const float* __restrict__ b1, f16* __restrict__ A1,
    f16* __restrict__ H1h, float* __restrict__ C0, float* __restrict__ C1,
    float* __restrict__ out, int s) {
  __shared__ float zred[4352];
  const int tid_ = threadIdx.x, lane_ = tid_ & 63, w_ = tid_ >> 6;
  const int bid_ = (int)blockIdx.x;
  const int i_ = ((bid_ & 7) << 5) + (bid_ >> 3);
  const int u0 = i_ * 4;
  const int j_ = lane_ & 15;
  const int kg_ = lane_ >> 4;
  const int ncol_ = (j_ >> 2) * 1024 + u0 + (j_ & 3);
  const int woff_ = ncol_ * 1024 + w_ * 256 + kg_ * 8;
  f16x8 bvU0[8], bvW1[8], bvU1[8];
#pragma unroll
  for (int kt = 0; kt < 8; ++kt) {
    bvU0[kt] = *(const f16x8*)(U0t + woff_ + kt * 32);
    bvW1[kt] = *(const f16x8*)(W1t + woff_ + kt * 32);
    bvU1[kt] = *(const f16x8*)(U1t + woff_ + kt * 32);
  }
  const int erow_ = tid_ >> 2;
  const int eu_ = u0 + (tid_ & 3);
  float bias1[4];
#pragma unroll
  for (int g = 0; g < 4; ++g) bias1[g] = b1[g * 1024 + eu_];

  float xz[4] = {0.f, 0.f, 0.f, 0.f};
  if (s < 256) {
    const f16* xrow = XZ + (size_t)(s * 64 + erow_) * 4096;
#pragma unroll
    for (int g = 0; g < 4; ++g) xz[g] = (float)xrow[g * 1024 + eu_];
  }
  float c0 = C0[erow_ * 1024 + eu_];
  float c1 = C1[erow_ * 1024 + eu_];
  step_once(s, u0, bvU0, bvW1, bvU1, bias1, xz, A1, H1h, 1, c0, c1, out,
            zred);
  C0[erow_ * 1024 + eu_] = c0;
  C1[erow_ * 1024 + eu_] = c1;
}

extern "C" void kernel_launch(void* const* d_in, const int* in_sizes, int n_in,
                              void* d_out, int out_size, void* d_ws, size_t ws_size,
                              hipStream_t stream) {
  (void)in_sizes; (void)n_in; (void)out_size;
  const int* tokens = (const int*)d_in[0];
  const float* emb = (const float*)d_in[1];
  const float* W0 = (const float*)d_in[2];
  const float* U0 = (const float*)d_in[3];
  const float* b0 = (const float*)d_in[4];
  const float* W1 = (const float*)d_in[5];
  const float* U1 = (const float*)d_in[6];
  const float* b1 = (const float*)d_in[7];
  float* out = (float*)d_out;

  // workspace carve-up; H1h LAST (coop path needs the full 256 slots)
  char* p = (char*)d_ws;
  f16* A0 = (f16*)p;   p += (size_t)16384 * 512 * 2;    // x tokens, fp16
  f16* A1 = (f16*)p;   p += (size_t)16384 * 1024 * 2;   // h0 history
  f16* W0t = (f16*)p;  p += (size_t)4096 * 512 * 2;     // W0^T
  f16* U0t = (f16*)p;  p += (size_t)4096 * 1024 * 2;    // U0^T
  f16* W1t = (f16*)p;  p += (size_t)4096 * 1024 * 2;    // W1^T
  f16* U1t = (f16*)p;  p += (size_t)4096 * 1024 * 2;    // U1^T
  f16* XZ = (f16*)p;   p += (size_t)16384 * 4096 * 2;   // xz0, rows t*64+b
  float* C0 = (float*)p; p += 64 * 1024 * 4;            // cell L0 (fallback)
  float* C1 = (float*)p; p += 64 * 1024 * 4;            // cell L1 (fallback)
  unsigned* arr0 = (unsigned*)p; p += 256 * 32 * 4;     // L0 arrive lines
  unsigned* rel0 = (unsigned*)p; p += 256 * 32 * 4;     // L0 release lines
  unsigned* arr1 = (unsigned*)p; p += 256 * 32 * 4;     // L1 arrive lines
  unsigned* rel1 = (unsigned*)p; p += 256 * 32 * 4;     // L1 release lines
  unsigned* mir = (unsigned*)p; p += 256 * 32 * 4;      // epoch mirrors
  f16* H1h = (f16*)p;                                   // h1 history slots
  const size_t need_coop = (size_t)(p - (char*)d_ws) + (size_t)256 * 65536 * 2;

  // weight transposes + casts
  k_transpose_f16<<<512, 256, 0, stream>>>(W0, W0t, 512, 4096);
  k_transpose_f16<<<1024, 256, 0, stream>>>(U0, U0t, 1024, 4096);
  k_transpose_f16<<<1024, 256, 0, stream>>>(W1, W1t, 1024, 4096);
  k_transpose_f16<<<1024, 256, 0, stream>>>(U1, U1t, 1024, 4096);

  // embedding
  k_embed_f16<<<8192, 256, 0, stream>>>(tokens, emb, A0);

  // layer 0 input projection: xz0 = x @ W0 + b0
  k_gemm_f16<<<4096, 256, 0, stream>>>(A0, W0t, b0, XZ, 16384, 4096, 512);

  hipMemsetAsync(C0, 0, 64 * 1024 * 4 * 2, stream);   // C0+C1
  hipMemsetAsync(arr0, 0, 5 * 256 * 32 * 4, stream);  // all flag arrays

  bool coop_ok = (ws_size >= need_coop);
  if (coop_ok) {
    const f16* XZc = XZ; const f16* U0c = U0t; const f16* W1c = W1t;
    const f16* U1c = U1t; const float* b1c = b1;
    f16* A1p = A1; f16* H1p = H1h; float* outp = out;
    unsigned* a0 = arr0; unsigned* r0 = rel0;
    unsigned* a1 = arr1; unsigned* r1 = rel1; unsigned* mr = mir;
    void* kargs[] = {(void*)&XZc, (void*)&U0c, (void*)&W1c, (void*)&U1c,
                     (void*)&b1c, (void*)&A1p, (void*)&H1p, (void*)&outp,
                     (void*)&a0, (void*)&r0, (void*)&a1, (void*)&r1,
                     (void*)&mr};
    hipError_t e = hipLaunchCooperativeKernel((const void*)k_scan6, dim3(512),
                                              dim3(256), kargs, 0, stream);
    if (e != hipSuccess) {
      (void)hipGetLastError();
      coop_ok = false;
    }
  }
  if (!coop_ok) {
    for (int s = 0; s <= 256; ++s)
      k_step<<<256, 256, 0, stream>>>(XZ, U0t, W1t, U1t, b1, A1, H1h, C0, C1,
                                      out, s);
  }
}

// Round 13
// 2233.386 us; speedup vs baseline: 1.4088x; 1.0818x over previous
//
#include <hip/hip_runtime.h>

// LSTM encoder: V=32000 E=512 U=1024 L=2, B=64 T=256.
// Round 13: r12 compute structure unchanged. (1) Barriers split into FOUR
// independent 128-block groups (layer x batch-half; halves never read each
// other's rows) -> straggler pool and gather fan-in halve. (2) h stores
// coalesced: LDS-stage 32x8 f16, then 32 threads store 16B dwordx4 sc0/sc1
// per row (256 -> 32 write-through txns/block) -> shorter drain tail.
// r12 lesson: weight "pins" land in AGPRs (unified file) -> VGPR_Count 108
// was fine all along; reloads were never the bottleneck.

typedef _Float16 f16;
typedef _Float16 f16x8 __attribute__((ext_vector_type(8)));
typedef _Float16 f16x4 __attribute__((ext_vector_type(4)));
typedef float f32x4 __attribute__((ext_vector_type(4)));

__device__ __forceinline__ f32x4 mfma16x32(f16x8 a, f16x8 b, f32x4 c) {
  return __builtin_amdgcn_mfma_f32_16x16x32_f16(a, b, c, 0, 0, 0);
}

__device__ __forceinline__ void gl_lds16(const void* g, void* l) {
  __builtin_amdgcn_global_load_lds(
      (const __attribute__((address_space(1))) void*)g,
      (__attribute__((address_space(3))) void*)l, 16, 0, 0);
}

__device__ __forceinline__ float sigmoidf_(float x) {
  return 1.0f / (1.0f + expf(-x));
}

// write-through stores: land at the L3 coherence point, no dirty L2 line
__device__ __forceinline__ void st_f16_sc(f16* p, float v) {
  f16 h = (f16)v;
  unsigned u = (unsigned)__builtin_bit_cast(unsigned short, h);
  asm volatile("global_store_short %0, %1, off sc0 sc1"
               :: "v"(p), "v"(u) : "memory");
}
__device__ __forceinline__ void st_b128_sc(f16* p, f16x8 v) {
  asm volatile("global_store_dwordx4 %0, %1, off sc0 sc1"
               :: "v"(p), "v"(v) : "memory");
}

__device__ __forceinline__ unsigned ld_flag(const unsigned* p) {
  return __hip_atomic_load(p, __ATOMIC_RELAXED, __HIP_MEMORY_SCOPE_AGENT);
}
__device__ __forceinline__ void st_flag(unsigned* p, unsigned v) {
  __hip_atomic_store(p, v, __ATOMIC_RELAXED, __HIP_MEMORY_SCOPE_AGENT);
}

// ---------- transpose + cast: D[n][k] = (f16)S[k][n] ----------
__global__ __launch_bounds__(256) void k_transpose_f16(
    const float* __restrict__ S, f16* __restrict__ D, int K, int N) {
  __shared__ float tile[64][65];
  int nk = K >> 6;
  int k0 = (blockIdx.x % nk) << 6;
  int n0 = (blockIdx.x / nk) << 6;
  int tc = threadIdx.x & 63;
  int tq = threadIdx.x >> 6;
#pragma unroll
  for (int r = 0; r < 16; ++r) {
    int kk = tq * 16 + r;
    tile[kk][tc] = S[(size_t)(k0 + kk) * N + (n0 + tc)];
  }
  __syncthreads();
#pragma unroll
  for (int r = 0; r < 16; ++r) {
    int nn = tq * 16 + r;
    D[(size_t)(n0 + nn) * K + (k0 + tc)] = (f16)tile[tc][nn];
  }
}

// ---------- embedding lookup -> fp16 A0[m][512], row m = t*64 + b ----------
__global__ __launch_bounds__(256) void k_embed_f16(
    const int* __restrict__ tok, const float* __restrict__ emb,
    f16* __restrict__ A0) {
  int i = blockIdx.x * 256 + threadIdx.x;
  int m = i >> 7;
  int e = (i & 127) << 2;
  int t = m >> 6, b = m & 63;
  int tk = tok[b * 256 + t];
  const float4 v = *(const float4*)(emb + (size_t)tk * 512 + e);
  f16x4 o = {(f16)v.x, (f16)v.y, (f16)v.z, (f16)v.w};
  *(f16x4*)(A0 + (size_t)m * 512 + e) = o;
}

// ---------- C[m][n] = (f16)(sum_k A[m][k]*Bt[n][k] + bias[n]) ----------
__global__ __launch_bounds__(256) void k_gemm_f16(
    const f16* __restrict__ A, const f16* __restrict__ Bt,
    const float* __restrict__ bias, f16* __restrict__ C,
    int M, int N, int K) {
  __shared__ f16 sA[2][128 * 32];
  __shared__ f16 sB[2][128 * 32];
  const int tid = threadIdx.x, lane = tid & 63, w = tid >> 6;
  const int mb = M >> 7;
  const int bm = blockIdx.x % mb, bn = blockIdx.x / mb;
  const int am0 = bm << 7, bn0 = bn << 7;
  const int wm = w >> 1, wn = w & 1;
  const int srow = lane >> 2, sch = lane & 3;

  f32x4 acc[4][4] = {};
  const int NT = K >> 5;
  int cur = 0;

  auto stage = [&](int kt, int buf) {
#pragma unroll
    for (int q2 = 0; q2 < 2; ++q2) {
      int q = w * 2 + q2;
      int row = q * 16 + srow;
      const f16* ga = A + (size_t)(am0 + row) * K + kt * 32 + sch * 8;
      const f16* gb = Bt + (size_t)(bn0 + row) * K + kt * 32 + sch * 8;
      gl_lds16(ga, (char*)&sA[buf][0] + q * 1024);
      gl_lds16(gb, (char*)&sB[buf][0] + q * 1024);
    }
  };

  stage(0, 0);
  __syncthreads();
  for (int kt = 0; kt < NT; ++kt) {
    if (kt + 1 < NT) stage(kt + 1, cur ^ 1);
    const f16* pa = &sA[cur][(wm * 64 + (lane & 15)) * 32 + (lane >> 4) * 8];
    const f16* pb = &sB[cur][(wn * 64 + (lane & 15)) * 32 + (lane >> 4) * 8];
    f16x8 av[4], bv[4];
#pragma unroll
    for (int mf = 0; mf < 4; ++mf) av[mf] = *(const f16x8*)(pa + mf * 512);
#pragma unroll
    for (int nf = 0; nf < 4; ++nf) bv[nf] = *(const f16x8*)(pb + nf * 512);
#pragma unroll
    for (int mf = 0; mf < 4; ++mf)
#pragma unroll
      for (int nf = 0; nf < 4; ++nf)
        acc[mf][nf] = mfma16x32(av[mf], bv[nf], acc[mf][nf]);
    __syncthreads();
    cur ^= 1;
  }

#pragma unroll
  for (int mf = 0; mf < 4; ++mf)
#pragma unroll
    for (int nf = 0; nf < 4; ++nf) {
      int col = bn0 + wn * 64 + nf * 16 + (lane & 15);
      float bs = bias[col];
#pragma unroll
      for (int r = 0; r < 4; ++r) {
        int row = am0 + wm * 64 + mf * 16 + (lane >> 4) * 4 + r;
        C[(size_t)row * N + col] = (f16)(acc[mf][nf][r] + bs);
      }
    }
}

// ---------- decoupled scan: 4 independent 128-block barrier groups ----------
// 512 blocks x 256 thr. bid<256: L0; else L1. rb=0..255 per layer:
//   ug = (rb&7)*16 + (rb>>3)&15  (unit-group, 8 units; XCD-local)
//   rh = rb>>7  (batch half), cid = rb&127 (id within group)
// Group (layer, rh): 128 blocks, own leader (cid 0) barrier.
__global__ __launch_bounds__(256, 2) void k_scan7(
    const f16* __restrict__ XZ, const f16* __restrict__ U0t,
    const f16* __restrict__ W1t, const f16* __restrict__ U1t,
    const float* __restrict__ b1, f16* __restrict__ A1,
    f16* __restrict__ H1h, float* __restrict__ out, unsigned* arr,
    unsigned* rel, unsigned* mir) {
  __shared__ float zred[4608];   // 2 sets x 4 waves x 32 rows x stride 18
  __shared__ f16 hstage[32][8];  // coalesced-store staging
  const int tid = threadIdx.x, lane = tid & 63, w = tid >> 6;
  const bool isL1 = (blockIdx.x >= 256);
  const int rb = isL1 ? (int)blockIdx.x - 256 : (int)blockIdx.x;
  const int ug = ((rb & 7) << 4) + ((rb >> 3) & 15);
  const int rh = rb >> 7;
  const int cid = rb & 127;
  const int u0 = ug * 8;
  const int j = lane & 15, kg = lane >> 4;
  const int aoff = (rh * 32 + j) * 1024 + w * 256 + kg * 8;
  // epilogue: one (row, unit) per thread
  const int erl = tid >> 3;
  const int eunit = tid & 7;
  const int q_e = eunit >> 2, euu = eunit & 3;
  const int erow = rh * 32 + erl;
  const int eu = u0 + eunit;
  // group flag bases
  unsigned* gArr = arr + (size_t)(((isL1 ? 2 : 0) + rh) * 128) * 32;
  unsigned* gRel = rel + (size_t)(((isL1 ? 2 : 0) + rh) * 128) * 32;
  unsigned* gMir = mir + (size_t)(rh * 128) * 32;

  // dual weight sets per wave (live in unified VGPR/AGPR file)
  const int wo0 = ((j >> 2) * 1024 + u0 + (j & 3)) * 1024 + w * 256 + kg * 8;
  const int wo1 = wo0 + 4 * 1024;
  f16x8 bA0[8], bA1[8], bB0[8], bB1[8];
  {
    const f16* base = isL1 ? W1t : U0t;
#pragma unroll
    for (int kt = 0; kt < 8; ++kt) {
      bA0[kt] = *(const f16x8*)(base + wo0 + kt * 32);
      bA1[kt] = *(const f16x8*)(base + wo1 + kt * 32);
    }
  }
  if (isL1) {
#pragma unroll
    for (int kt = 0; kt < 8; ++kt) {
      bB0[kt] = *(const f16x8*)(U1t + wo0 + kt * 32);
      bB1[kt] = *(const f16x8*)(U1t + wo1 + kt * 32);
    }
  }
  float c = 0.0f;  // this thread's (row,unit) cell state

  if (!isL1) {
    // ================= layer 0 =================
    float xz[4];
#pragma unroll
    for (int g = 0; g < 4; ++g)
      xz[g] = (float)XZ[(size_t)erow * 4096 + g * 1024 + eu];

    for (int s = 0; s < 256; ++s) {
      f32x4 a0[2] = {}, a1[2] = {};
      if (s > 0) {
        const f16* ap = A1 + (size_t)(s - 1) * 65536 + aoff;
#pragma unroll
        for (int kt = 0; kt < 8; ++kt)
#pragma unroll
          for (int mf = 0; mf < 2; ++mf) {
            f16x8 av = *(const f16x8*)(ap + mf * 16384 + kt * 32);
            a0[mf] = mfma16x32(av, bA0[kt], a0[mf]);
            a1[mf] = mfma16x32(av, bA1[kt], a1[mf]);
          }
      }
#pragma unroll
      for (int mf = 0; mf < 2; ++mf)
#pragma unroll
        for (int r = 0; r < 4; ++r) {
          zred[w * 576 + (mf * 16 + kg * 4 + r) * 18 + j] = a0[mf][r];
          zred[2304 + w * 576 + (mf * 16 + kg * 4 + r) * 18 + j] = a1[mf][r];
        }
      __syncthreads();
      float z[4];
#pragma unroll
      for (int g = 0; g < 4; ++g) {
        float sm = xz[g];
#pragma unroll
        for (int wv = 0; wv < 4; ++wv)
          sm += zred[q_e * 2304 + wv * 576 + erl * 18 + g * 4 + euu];
        z[g] = sm;
      }
      float gi = sigmoidf_(z[0]), gf = sigmoidf_(z[1]);
      float gg = tanhf(z[2]), go = sigmoidf_(z[3]);
      c = gf * c + gi * gg;
      hstage[erl][eunit] = (f16)(go * tanhf(c));
      __syncthreads();
      if (tid < 32)
        st_b128_sc(&A1[(size_t)(s * 64 + rh * 32 + tid) * 1024 + u0],
                   *(const f16x8*)hstage[tid]);

      // drain stores, then prefetch next xz (completes under barrier wait)
      asm volatile("s_waitcnt vmcnt(0)" ::: "memory");
      float xzn[4] = {0.f, 0.f, 0.f, 0.f};
      if (s + 1 < 256) {
        const f16* xrow = XZ + (size_t)((s + 1) * 64 + erow) * 4096;
#pragma unroll
        for (int g = 0; g < 4; ++g) xzn[g] = (float)xrow[g * 1024 + eu];
      }
      __syncthreads();

      // group barrier0(s); afterwards half-epoch = s+1 (A1[0..s] visible)
      const unsigned v = (unsigned)s + 1u;
      if (cid == 0) {
        if (tid >= 1 && tid < 128) {
          while (ld_flag(&gArr[(unsigned)tid * 32u]) < v)
            __builtin_amdgcn_s_sleep(1);
        }
        __syncthreads();  // all 127 arrivals observed
        if (tid >= 1 && tid < 128) st_flag(&gRel[(unsigned)tid * 32u], v);
        if (tid < 128) st_flag(&gMir[(unsigned)tid * 32u], v);
      } else {
        if (tid == 0) {
          st_flag(&gArr[(unsigned)cid * 32u], v);
          while (ld_flag(&gRel[(unsigned)cid * 32u]) < v)
            __builtin_amdgcn_s_sleep(1);
        }
        __syncthreads();
      }
#pragma unroll
      for (int g = 0; g < 4; ++g) xz[g] = xzn[g];
    }
  } else {
    // ================= layer 1 =================
    float bias1[4];
#pragma unroll
    for (int g = 0; g < 4; ++g) bias1[g] = b1[g * 1024 + eu];

    // prime: wait half-epoch 1, compute accW = W1 * h0(0)
    if (tid == 0) {
      while (ld_flag(&gMir[(unsigned)cid * 32u]) < 1u)
        __builtin_amdgcn_s_sleep(1);
    }
    __syncthreads();
    f32x4 accW0[2] = {}, accW1[2] = {};
    {
      const f16* ap = A1 + aoff;
#pragma unroll
      for (int kt = 0; kt < 8; ++kt)
#pragma unroll
        for (int mf = 0; mf < 2; ++mf) {
          f16x8 av = *(const f16x8*)(ap + mf * 16384 + kt * 32);
          accW0[mf] = mfma16x32(av, bA0[kt], accW0[mf]);
          accW1[mf] = mfma16x32(av, bA1[kt], accW1[mf]);
        }
    }

    for (int t = 0; t < 256; ++t) {
      f32x4 a0[2] = {accW0[0], accW0[1]};
      f32x4 a1[2] = {accW1[0], accW1[1]};
      if (t > 0) {
        const f16* hp = H1h + (size_t)(t - 1) * 65536 + aoff;
#pragma unroll
        for (int kt = 0; kt < 8; ++kt)
#pragma unroll
          for (int mf = 0; mf < 2; ++mf) {
            f16x8 av = *(const f16x8*)(hp + mf * 16384 + kt * 32);
            a0[mf] = mfma16x32(av, bB0[kt], a0[mf]);
            a1[mf] = mfma16x32(av, bB1[kt], a1[mf]);
          }
      }
#pragma unroll
      for (int mf = 0; mf < 2; ++mf)
#pragma unroll
        for (int r = 0; r < 4; ++r) {
          zred[w * 576 + (mf * 16 + kg * 4 + r) * 18 + j] = a0[mf][r];
          zred[2304 + w * 576 + (mf * 16 + kg * 4 + r) * 18 + j] = a1[mf][r];
        }
      __syncthreads();
      float z[4];
#pragma unroll
      for (int g = 0; g < 4; ++g) {
        float sm = bias1[g];
#pragma unroll
        for (int wv = 0; wv < 4; ++wv)
          sm += zred[q_e * 2304 + wv * 576 + erl * 18 + g * 4 + euu];
        z[g] = sm;
      }
      float gi = sigmoidf_(z[0]), gf = sigmoidf_(z[1]);
      float gg = tanhf(z[2]), go = sigmoidf_(z[3]);
      c = gf * c + gi * gg;
      float hn = go * tanhf(c);
      if (t == 255) {
        out[(size_t)erow * 262144 + (size_t)t * 1024 + eu] = hn;
        out[16777216 + erow * 1024 + eu] = hn;
        out[16777216 + 65536 + erow * 1024 + eu] = c;
        break;  // last step: no publish/barrier needed
      }
      hstage[erl][eunit] = (f16)hn;
      __syncthreads();
      if (tid < 32)
        st_b128_sc(&H1h[(size_t)t * 65536 + (rh * 32 + tid) * 1024 + u0],
                   *(const f16x8*)hstage[tid]);

      // barrier1(t) with W1-pass overlap in the wait window
      asm volatile("s_waitcnt vmcnt(0)" ::: "memory");
      __syncthreads();
      const unsigned v = (unsigned)t + 1u;
      if (cid == 0) {
        // leader: gather + release FIRST so workers aren't held up
        if (tid >= 1 && tid < 128) {
          while (ld_flag(&gArr[(unsigned)tid * 32u]) < v)
            __builtin_amdgcn_s_sleep(1);
        }
        __syncthreads();
        if (tid >= 1 && tid < 128) st_flag(&gRel[(unsigned)tid * 32u], v);
      } else {
        if (tid == 0) st_flag(&gArr[(unsigned)cid * 32u], v);
      }
      // deferred out store: hides under the epoch/release waits
      out[(size_t)erow * 262144 + (size_t)t * 1024 + eu] = hn;
      // overlap: next step's W1 pass, gated on half-epoch t+2
      if (tid == 0) {
        while (ld_flag(&gMir[(unsigned)cid * 32u]) < v + 1u)
          __builtin_amdgcn_s_sleep(1);
      }
      __syncthreads();
      {
        const f16* ap = A1 + (size_t)(t + 1) * 65536 + aoff;
        f32x4 t0[2] = {}, t1[2] = {};
#pragma unroll
        for (int kt = 0; kt < 8; ++kt)
#pragma unroll
          for (int mf = 0; mf < 2; ++mf) {
            f16x8 av = *(const f16x8*)(ap + mf * 16384 + kt * 32);
            t0[mf] = mfma16x32(av, bA0[kt], t0[mf]);
            t1[mf] = mfma16x32(av, bA1[kt], t1[mf]);
          }
#pragma unroll
        for (int mf = 0; mf < 2; ++mf) {
          accW0[mf] = t0[mf];
          accW1[mf] = t1[mf];
        }
      }
      // wait for release (workers; leader already released)
      if (cid != 0) {
        if (tid == 0) {
          while (ld_flag(&gRel[(unsigned)cid * 32u]) < v)
            __builtin_amdgcn_s_sleep(1);
        }
        __syncthreads();
      }
    }
  }
}

// ---------- fallback: fused per-step kernel (r9/r10, proven) ----------
__device__ __forceinline__ void reduce4(const f32x4 acc[4], float* zred,
                                        float z[4]) {
  const int tid = threadIdx.x, lane = tid & 63, w = tid >> 6;
  const int j = lane & 15, kg = lane >> 4;
#pragma unroll
  for (int mf = 0; mf < 4; ++mf)
#pragma unroll
    for (int r = 0; r < 4; ++r)
      zred[w * 1088 + (mf * 16 + kg * 4 + r) * 17 + j] = acc[mf][r];
  __syncthreads();
  const int erow = tid >> 2, euu = tid & 3;
#pragma unroll
  for (int g = 0; g < 4; ++g) {
#pragma unroll
    for (int wv = 0; wv < 4; ++wv)
      z[g] += zred[wv * 1088 + erow * 17 + g * 4 + euu];
  }
}

__device__ __forceinline__ void step_once(
    int s, int u0, const f16x8 bvU0[8], const f16x8 bvW1[8],
    const f16x8 bvU1[8], const float bias1[4], const float xz[4],
    f16* __restrict__ A1, f16* __restrict__ H1h, int hmask,
    float& c0, float& c1, float* __restrict__ out, float* zred) {
  const int tid = threadIdx.x, lane = tid & 63, w = tid >> 6;
  const int j = lane & 15, kg = lane >> 4;
  const int aoff = j * 1024 + w * 256 + kg * 8;
  const int erow = tid >> 2;
  const int eu = u0 + (tid & 3);

  f32x4 accA[4] = {};
  f32x4 accB[4] = {};

  if (s >= 1) {
    const f16* ap = A1 + (size_t)(s - 1) * 65536 + aoff;
#pragma unroll
    for (int kt = 0; kt < 8; ++kt)
#pragma unroll
      for (int mf = 0; mf < 4; ++mf) {
        f16x8 av = *(const f16x8*)(ap + mf * 16384 + kt * 32);
        if (s < 256) accA[mf] = mfma16x32(av, bvU0[kt], accA[mf]);
        accB[mf] = mfma16x32(av, bvW1[kt], accB[mf]);
      }
    if (s >= 2) {
      const f16* hp = H1h + (size_t)((s - 2) & hmask) * 65536 + aoff;
#pragma unroll
      for (int kt = 0; kt < 8; ++kt)
#pragma unroll
        for (int mf = 0; mf < 4; ++mf)
          accB[mf] = mfma16x32(*(const f16x8*)(hp + mf * 16384 + kt * 32),
                               bvU1[kt], accB[mf]);
    }
  }

  if (s < 256) {
    float z[4] = {xz[0], xz[1], xz[2], xz[3]};
    reduce4(accA, zred, z);
    float gi = sigmoidf_(z[0]), gf = sigmoidf_(z[1]);
    float gg = tanhf(z[2]), go = sigmoidf_(z[3]);
    c0 = gf * c0 + gi * gg;
    st_f16_sc(&A1[(size_t)(s * 64 + erow) * 1024 + eu], go * tanhf(c0));
  }
  __syncthreads();

  if (s >= 1) {
    const int t = s - 1;
    float z[4] = {bias1[0], bias1[1], bias1[2], bias1[3]};
    reduce4(accB, zred, z);
    float gi = sigmoidf_(z[0]), gf = sigmoidf_(z[1]);
    float gg = tanhf(z[2]), go = sigmoidf_(z[3]);
    c1 = gf * c1 + gi * gg;
    float hn = go * tanhf(c1);
    st_f16_sc(&H1h[(size_t)(t & hmask) * 65536 + erow * 1024 + eu], hn);
    out[(size_t)erow * 262144 + (size_t)t * 1024 + eu] = hn;
    if (t == 255) {
      out[16777216 + erow * 1024 + eu] = hn;
      out[16777216 + 65536 + erow * 1024 + eu] = c1;
    }
  }
}

__global__ __launch_bounds__(256, 1) void k_step(
    const f16* __restrict__ XZ, const f16* __restrict__ U0t,
    const f16* __restrict__ W1t, const f16* __restrict__ U1t,
    const float* __restrict__ b1, f16* __restrict__ A1,
    f16* __restrict__ H1h, float* __restrict__ C0, float* __restrict__ C1,
    float* __restrict__ out, int s) {
  __shared__ float zred[4352];
  const int tid_ = threadIdx.x, lane_ = tid_ & 63, w_ = tid_ >> 6;
  const int bid_ = (int)blockIdx.x;
  const int i_ = ((bid_ & 7) << 5) + (bid_ >> 3);
  const int u0 = i_ * 4;
  const int j_ = lane_ & 15;
  const int kg_ = lane_ >> 4;
  const int ncol_ = (j_ >> 2) * 1024 + u0 + (j_ & 3);
  const int woff_ = ncol_ * 1024 + w_ * 256 + kg_ * 8;
  f16x8 bvU0[8], bvW1[8], bvU1[8];
#pragma unroll
  for (int kt = 0; kt < 8; ++kt) {
    bvU0[kt] = *(const f16x8*)(U0t + woff_ + kt * 32);
    bvW1[kt] = *(const f16x8*)(W1t + woff_ + kt * 32);
    bvU1[kt] = *(const f16x8*)(U1t + woff_ + kt * 32);
  }
  const int erow_ = tid_ >> 2;
  const int eu_ = u0 + (tid_ & 3);
  float bias1[4];
#pragma unroll
  for (int g = 0; g < 4; ++g) bias1[g] = b1[g * 1024 + eu_];

  float xz[4] = {0.f, 0.f, 0.f, 0.f};
  if (s < 256) {
    const f16* xrow = XZ + (size_t)(s * 64 + erow_) * 4096;
#pragma unroll
    for (int g = 0; g < 4; ++g) xz[g] = (float)xrow[g * 1024 + eu_];
  }
  float c0 = C0[erow_ * 1024 + eu_];
  float c1 = C1[erow_ * 1024 + eu_];
  step_once(s, u0, bvU0, bvW1, bvU1, bias1, xz, A1, H1h, 1, c0, c1, out,
            zred);
  C0[erow_ * 1024 + eu_] = c0;
  C1[erow_ * 1024 + eu_] = c1;
}

extern "C" void kernel_launch(void* const* d_in, const int* in_sizes, int n_in,
                              void* d_out, int out_size, void* d_ws, size_t ws_size,
                              hipStream_t stream) {
  (void)in_sizes; (void)n_in; (void)out_size;
  const int* tokens = (const int*)d_in[0];
  const float* emb = (const float*)d_in[1];
  const float* W0 = (const float*)d_in[2];
  const float* U0 = (const float*)d_in[3];
  const float* b0 = (const float*)d_in[4];
  const float* W1 = (const float*)d_in[5];
  const float* U1 = (const float*)d_in[6];
  const float* b1 = (const float*)d_in[7];
  float* out = (float*)d_out;

  // workspace carve-up; H1h LAST (coop path needs the full 256 slots)
  char* p = (char*)d_ws;
  f16* A0 = (f16*)p;   p += (size_t)16384 * 512 * 2;    // x tokens, fp16
  f16* A1 = (f16*)p;   p += (size_t)16384 * 1024 * 2;   // h0 history
  f16* W0t = (f16*)p;  p += (size_t)4096 * 512 * 2;     // W0^T
  f16* U0t = (f16*)p;  p += (size_t)4096 * 1024 * 2;    // U0^T
  f16* W1t = (f16*)p;  p += (size_t)4096 * 1024 * 2;    // W1^T
  f16* U1t = (f16*)p;  p += (size_t)4096 * 1024 * 2;    // U1^T
  f16* XZ = (f16*)p;   p += (size_t)16384 * 4096 * 2;   // xz0, rows t*64+b
  float* C0 = (float*)p; p += 64 * 1024 * 4;            // cell L0 (fallback)
  float* C1 = (float*)p; p += 64 * 1024 * 4;            // cell L1 (fallback)
  unsigned* arr = (unsigned*)p; p += 4 * 128 * 32 * 4;  // arrive lines (4 grp)
  unsigned* rel = (unsigned*)p; p += 4 * 128 * 32 * 4;  // release lines
  unsigned* mir = (unsigned*)p; p += 2 * 128 * 32 * 4;  // epoch mirrors (half)
  f16* H1h = (f16*)p;                                   // h1 history slots
  const size_t need_coop = (size_t)(p - (char*)d_ws) + (size_t)256 * 65536 * 2;

  // weight transposes + casts
  k_transpose_f16<<<512, 256, 0, stream>>>(W0, W0t, 512, 4096);
  k_transpose_f16<<<1024, 256, 0, stream>>>(U0, U0t, 1024, 4096);
  k_transpose_f16<<<1024, 256, 0, stream>>>(W1, W1t, 1024, 4096);
  k_transpose_f16<<<1024, 256, 0, stream>>>(U1, U1t, 1024, 4096);

  // embedding
  k_embed_f16<<<8192, 256, 0, stream>>>(tokens, emb, A0);

  // layer 0 input projection: xz0 = x @ W0 + b0
  k_gemm_f16<<<4096, 256, 0, stream>>>(A0, W0t, b0, XZ, 16384, 4096, 512);

  hipMemsetAsync(C0, 0, 64 * 1024 * 4 * 2, stream);       // C0+C1
  hipMemsetAsync(arr, 0, 10 * 128 * 32 * 4, stream);      // arr+rel+mir

  bool coop_ok = (ws_size >= need_coop);
  if (coop_ok) {
    const f16* XZc = XZ; const f16* U0c = U0t; const f16* W1c = W1t;
    const f16* U1c = U1t; const float* b1c = b1;
    f16* A1p = A1; f16* H1p = H1h; float* outp = out;
    unsigned* ar = arr; unsigned* rl = rel; unsigned* mr = mir;
    void* kargs[] = {(void*)&XZc, (void*)&U0c, (void*)&W1c, (void*)&U1c,
                     (void*)&b1c, (void*)&A1p, (void*)&H1p, (void*)&outp,
                     (void*)&ar, (void*)&rl, (void*)&mr};
    hipError_t e = hipLaunchCooperativeKernel((const void*)k_scan7, dim3(512),
                                              dim3(256), kargs, 0, stream);
    if (e != hipSuccess) {
      (void)hipGetLastError();
      coop_ok = false;
    }
  }
  if (!coop_ok) {
    for (int s = 0; s <= 256; ++s)
      k_step<<<256, 256, 0, stream>>>(XZ, U0t, W1t, U1t, b1, A1, H1h, C0, C1,
                                      out, s);
  }
}